// Round 18
// baseline (750.668 us; speedup 1.0000x reference)
//
#include <hip/hip_runtime.h>

typedef unsigned short u16;
typedef unsigned int   u32;

#define N_NODES    15000
#define PADN       15008
#define N_EDGES    30000
#define NUM_GRAPHS 600
#define N_STEMS    6000
#define N_JBONDS   3000

#define OUT_FINAL  0
#define OUT_STEM   1200
#define OUT_JB     631200

#define A1S 68                // a1b (global) row stride u16
#define N_CVT 26

// ---- edge-GEMM geometry ----
#define EBLK 64               // edges per block
#define EGRID2 469            // ceil(30000/64)
#define KCH 130               // K chunks of 32 (K = 65*64 = 4160, kidx = k*64 + j)
#define KHALF 65              // chunks per K-half
#define A1LS 66               // a1l row stride u16
#define O2S 66                // outs2 row stride dw (== 2 mod 32 -> 2-way (free) A-gen reads)

// ---- k_node geometry ----
#define NGRID 235
#define NGROUPS32 (PADN/32)   // 469 groups of 32 nodes

typedef short frag8 __attribute__((ext_vector_type(8)));   // 8 bf16
typedef float facc4 __attribute__((ext_vector_type(4)));   // 4 f32 acc

__device__ __forceinline__ float u2f(u16 v){ union{u32 i; float f;} c; c.i=((u32)v)<<16; return c.f; }
__device__ __forceinline__ float blo(u32 x){ union{u32 i; float f;} c; c.i=x<<16; return c.f; }
__device__ __forceinline__ float bhi(u32 x){ union{u32 i; float f;} c; c.i=x&0xffff0000u; return c.f; }
__device__ __forceinline__ u16  f2b(float f){ union{float f; u32 u;} c; c.f=f; u32 u=c.u;
                                              return (u16)((u + 0x7fffu + ((u>>16)&1u))>>16); }
__device__ __forceinline__ float lrelu(float x){ return x>0.f ? x : 0.01f*x; }
__device__ __forceinline__ float sigmoidf(float x){ return 1.f/(1.f+expf(-x)); }

__device__ __forceinline__ int lower_bound_i(const int* __restrict__ a, int n, int v){
  int lo=0, hi=n;
  while(lo<hi){ int m=(lo+hi)>>1; if(a[m]<v) lo=m+1; else hi=m; }
  return lo;
}

__device__ __forceinline__ void store_out(void* dout, int isf, int idx, float v){
  if(isf) ((float*)dout)[idx] = v;
  else    ((u16*)dout)[idx]   = f2b(v);
}

// ---------------- dtype sniff ----------------
__global__ __launch_bounds__(256) void k_sniff(const u16* __restrict__ x, int n, int* __restrict__ flag){
  int i = blockIdx.x*256 + threadIdx.x;
  int local = 0;
  for(; i < n; i += gridDim.x*256){
    u16 v = x[i];
    if(((v>>7)&0xFFu) == 0xFFu) local = 1;
  }
  if(local) atomicOr(flag, 1);
}

// ---------------- convert float inputs to f32 ----------------
struct CvtArgs { const void* src[N_CVT]; float* dst[N_CVT]; int n[N_CVT]; };

__global__ __launch_bounds__(256) void k_cvt(CvtArgs A, const int* __restrict__ flag){
  int isf = *flag;
  int tid = blockIdx.x*256 + threadIdx.x;
  int stride = gridDim.x*256;
  for(int b=0; b<N_CVT; b++){
    int n = A.n[b];
    const float* sf = (const float*)A.src[b];
    const u16*   sb = (const u16*)A.src[b];
    float* d = A.dst[b];
    for(int i=tid; i<n; i+=stride) d[i] = isf ? sf[i] : u2f(sb[i]);
  }
}

// ---------------- lin0 (writes f32 out + bf16 mirror) ----------------
__global__ __launch_bounds__(64) void k_lin0(const float* __restrict__ x, const float* __restrict__ w,
                                             const float* __restrict__ b,
                                             float* __restrict__ outF, u16* __restrict__ outB){
  int n = blockIdx.x, o = threadIdx.x;
  __shared__ float xs[14];
  if(o<14) xs[o] = x[n*14+o];
  __syncthreads();
  float acc = b[o];
  #pragma unroll
  for(int i=0;i<14;i++) acc += xs[i]*w[o*14+i];
  float v = lrelu(acc);
  outF[n*64+o] = v;
  outB[n*64+o] = f2b(v);
}

// ---------------- a1b[e][A1S] bf16 ----------------
__global__ __launch_bounds__(128) void k_a1(const float* __restrict__ ea,
                                            const float* __restrict__ en1w, const float* __restrict__ en1b,
                                            u16* __restrict__ a1b){
  int e = blockIdx.x, k = threadIdx.x;
  if(k >= A1S) return;
  float v = 0.f;
  if(k < 64){
    float acc = en1b[k];
    #pragma unroll
    for(int c=0;c<4;c++) acc += ea[e*4+c] * en1w[k*4+c];
    v = lrelu(acc);
  } else if(k == 64) v = 1.0f;
  a1b[e*A1S + k] = f2b(v);
}

// ---------------- B2b: bf16 B-operand, FRAGMENT-LINEAR order ----------------
__global__ __launch_bounds__(256) void k_packW2b(const float* __restrict__ en2w, const float* __restrict__ en2b,
                                                 u16* __restrict__ B2b){
  int idx = blockIdx.x*256 + threadIdx.x;
  if(idx >= KCH*2048) return;
  int jj  = idx & 7;
  int l   = (idx >> 3) & 63;
  int nt  = (idx >> 9) & 3;
  int c   = idx >> 11;
  int q = l >> 4, m16 = l & 15;
  int kidx = c*32 + q*8 + jj;
  int k = kidx >> 6, j = kidx & 63;
  int o = nt*16 + m16;
  float v = (k < 64) ? en2w[((size_t)(j*64 + o))*64 + k] : en2b[j*64 + o];
  B2b[idx] = f2b(v);
}

// ---------------- packed coalesced weights for k_node ----------------
__global__ __launch_bounds__(256) void k_packRoot(const float* __restrict__ root, float4* __restrict__ rootP){
  int idx = blockIdx.x*256 + threadIdx.x;
  if(idx >= 1024) return;
  int o = idx & 63, j4 = idx >> 6;
  float4 v;
  v.x = root[(4*j4+0)*64 + o];
  v.y = root[(4*j4+1)*64 + o];
  v.z = root[(4*j4+2)*64 + o];
  v.w = root[(4*j4+3)*64 + o];
  rootP[idx] = v;
}

__global__ __launch_bounds__(256) void k_packGates(const float* __restrict__ wih, const float* __restrict__ whh,
                                                   float4* __restrict__ wihP, float4* __restrict__ whhP){
  int idx = blockIdx.x*256 + threadIdx.x;
  if(idx >= 3072) return;
  int o = idx & 63, j4 = (idx >> 6) & 15, g = idx >> 10;
  int row = (g*64 + o)*64 + 4*j4;
  float4 a, b;
  a.x = wih[row+0]; a.y = wih[row+1]; a.z = wih[row+2]; a.w = wih[row+3];
  b.x = whh[row+0]; b.y = whh[row+1]; b.z = whh[row+2]; b.w = whh[row+3];
  wihP[idx] = a; whhP[idx] = b;
}

// ---------------- packed coalesced head weights ----------------
__global__ __launch_bounds__(256) void k_packHeads(const float* __restrict__ s1w, const float* __restrict__ s2w,
                                                   const float* __restrict__ j1w,
                                                   float4* __restrict__ s1P, float4* __restrict__ s2P,
                                                   float4* __restrict__ j1P){
  int idx = blockIdx.x*256 + threadIdx.x;
  if(idx < 1024){
    int o = idx & 63, j4 = idx >> 6;
    const float* r = s1w + o*64 + 4*j4;
    s1P[idx] = (float4){r[0], r[1], r[2], r[3]};
    const float* r2 = j1w + o*64 + 4*j4;
    j1P[idx] = (float4){r2[0], r2[1], r2[2], r2[3]};
  }
  if(idx < 1792){
    int j4 = idx / 112, t = idx % 112;
    float4 v = {0.f,0.f,0.f,0.f};
    if(t < 105){
      const float* r = s2w + t*64 + 4*j4;
      v = (float4){r[0], r[1], r[2], r[3]};
    }
    s2P[idx] = v;
  }
}

// ---------------- deg ----------------
__global__ __launch_bounds__(256) void k_deg(const int* __restrict__ dst, float* __restrict__ deg){
  int e = blockIdx.x*256 + threadIdx.x;
  if(e < N_EDGES) atomicAdd(&deg[dst[e]], 1.0f);
}

// ---------------- edge-GEMM v4 (unchanged) ----------------
__global__ __launch_bounds__(256, 2) void k_egemm(const u16* __restrict__ outB,
                                               const u16* __restrict__ a1b,
                                               const u16* __restrict__ B2b,
                                               const int* __restrict__ ei,
                                               float* __restrict__ agg){
  int tid = threadIdx.x;
  int l = tid & 63, w = tid >> 6;
  int m16 = l & 15, q = l >> 4;
  int half = blockIdx.x & 1;
  int eb = (blockIdx.x >> 1) * EBLK;

  __shared__ __align__(16) u16 a1l[EBLK*A1LS];
  __shared__ __align__(16) u32 outs2[32*O2S];
  __shared__ __align__(16) u16 Bl[4*2048];
  __shared__ int dstl[EBLK];

  for(int i = tid; i < EBLK; i += 256){
    int e = eb + i;
    dstl[i] = (e < N_EDGES) ? ei[N_EDGES + e] : -1;
  }
  for(int idx = tid; idx < EBLK*33; idx += 256){
    int r = idx / 33, c = idx - r*33;
    int e = eb + r;
    u32 v = (e < N_EDGES) ? ((const u32*)(a1b + (size_t)e*A1S))[c] : 0u;
    ((u32*)a1l)[r*33 + c] = v;
  }
  for(int idx = tid; idx < EBLK*8; idx += 256){
    int r = idx >> 3, part = idx & 7;
    int e = eb + r;
    int node = (e < N_EDGES) ? ei[e] : 0;
    uint4 v = *(const uint4*)(outB + (size_t)node*64 + part*8);
    outs2[(part*4+0)*O2S + r] = v.x;
    outs2[(part*4+1)*O2S + r] = v.y;
    outs2[(part*4+2)*O2S + r] = v.z;
    outs2[(part*4+3)*O2S + r] = v.w;
  }
  __syncthreads();

  facc4 acc[4];
  #pragma unroll
  for(int nt=0;nt<4;nt++) acc[nt] = (facc4){0.f,0.f,0.f,0.f};

  int el0 = w*16 + m16;
  int cbase = half * KHALF;
  for(int rr = 0; rr < 17; rr++){
    int c0 = rr*4;
    int nch = KHALF - c0; if(nch > 4) nch = 4;
    {
      const uint4* src = (const uint4*)(B2b + (size_t)(cbase + c0)*2048);
      for(int i = tid; i < nch*256; i += 256) ((uint4*)Bl)[i] = src[i];
    }
    __syncthreads();
    for(int cc = 0; cc < nch; cc++){
      int c = cbase + c0 + cc;
      int k = c >> 1;
      int jdw0 = ((c & 1) << 4) + (q << 2);
      float av = u2f(a1l[el0*A1LS + k]);
      union { u32 d[4]; frag8 f; } au;
      #pragma unroll
      for(int i=0;i<4;i++){
        u32 d0 = outs2[(jdw0+i)*O2S + el0];
        float plo = blo(d0)*av, phi = bhi(d0)*av;
        au.d[i] = __builtin_amdgcn_perm(__float_as_uint(phi)+0x8000u,
                                        __float_as_uint(plo)+0x8000u, 0x07060302u);
      }
      #pragma unroll
      for(int nt = 0; nt < 4; nt++){
        frag8 bf = *(const frag8*)(Bl + ((size_t)((cc*4 + nt)*64 + l))*8);
        acc[nt] = __builtin_amdgcn_mfma_f32_16x16x32_bf16(au.f, bf, acc[nt], 0,0,0);
      }
    }
    __syncthreads();
  }

  #pragma unroll
  for(int nt = 0; nt < 4; nt++){
    #pragma unroll
    for(int r = 0; r < 4; r++){
      int el = w*16 + q*4 + r;
      int dst = dstl[el];
      if(dst >= 0) atomicAdd(&agg[(size_t)dst*64 + nt*16 + m16], acc[nt][r]);
    }
  }
}

// ---------------- node update v10: persistent, 32-node groups, 4 nodes/thread ----------------
// LDS reads per node-j4 drop 5 -> 3.5; barriers per 32 nodes halve. (512,1) = 2 waves/SIMD
// -> ~512 VGPR budget/wave: no spill risk at 24 acc + 32 state + 4 weight live floats.
__global__ __launch_bounds__(512, 1) void k_node(float* __restrict__ agg, const float* __restrict__ deg,
                                              float* __restrict__ outF, u16* __restrict__ outB,
                                              const float4* __restrict__ rootP, const float* __restrict__ convb,
                                              const float4* __restrict__ wihP, const float4* __restrict__ whhP,
                                              const float* __restrict__ bih, const float* __restrict__ bhh){
  int o = threadIdx.x & 63, g = threadIdx.x >> 6;   // g 0..7 -> nodes g*4..g*4+3
  __shared__ __align__(16) float outs[32][64], ms[32][64];   // 16 KB
  __shared__ __align__(16) float4 rootL[1024];
  __shared__ __align__(16) float4 wihL[3072];
  __shared__ __align__(16) float4 whhL[3072];

  for(int i = threadIdx.x; i < 1024; i += 512) rootL[i] = rootP[i];
  for(int i = threadIdx.x; i < 3072; i += 512){ wihL[i] = wihP[i]; whhL[i] = whhP[i]; }
  float cb = convb[o];
  float b0 = bih[o], b1 = bih[64+o], b2 = bih[128+o];
  float c0 = bhh[o], c1 = bhh[64+o], c2 = bhh[128+o];

  for(int ng = blockIdx.x; ng < NGROUPS32; ng += gridDim.x){
    int nb = ng * 32;
    __syncthreads();   // weights staged (first iter) / prev-iter LDS reads done
    ((float4*)outs)[threadIdx.x] = ((const float4*)(outF + (size_t)nb*64))[threadIdx.x];
    __syncthreads();

    int n0 = nb + g*4;
    const float4* op[4];
    #pragma unroll
    for(int i=0;i<4;i++) op[i] = (const float4*)outs[g*4+i];

    float acc[4];
    #pragma unroll
    for(int i=0;i<4;i++){
      acc[i] = agg[(size_t)(n0+i)*64+o] / fmaxf(deg[n0+i], 1.0f) + cb;
      agg[(size_t)(n0+i)*64+o] = 0.f;
    }
    #pragma unroll 4
    for(int j4=0;j4<16;j4++){
      float4 w = rootL[j4*64+o];
      #pragma unroll
      for(int i=0;i<4;i++){
        float4 m = op[i][j4];
        acc[i] += w.x*m.x + w.y*m.y + w.z*m.z + w.w*m.w;
      }
    }
    #pragma unroll
    for(int i=0;i<4;i++) ms[g*4+i][o] = lrelu(acc[i]);
    __syncthreads();

    float ir[4], iz[4], in_[4], hr[4], hz[4], hn[4];
    #pragma unroll
    for(int i=0;i<4;i++){ ir[i]=b0; iz[i]=b1; in_[i]=b2; hr[i]=c0; hz[i]=c1; hn[i]=c2; }
    #pragma unroll 2
    for(int j4=0;j4<16;j4++){
      float4 m4[4], h4[4];
      #pragma unroll
      for(int i=0;i<4;i++){
        m4[i] = ((const float4*)ms[g*4+i])[j4];
        h4[i] = op[i][j4];
      }
      float4 a;
      a = wihL[(0*16+j4)*64+o];
      #pragma unroll
      for(int i=0;i<4;i++) ir[i]  += m4[i].x*a.x+m4[i].y*a.y+m4[i].z*a.z+m4[i].w*a.w;
      a = wihL[(1*16+j4)*64+o];
      #pragma unroll
      for(int i=0;i<4;i++) iz[i]  += m4[i].x*a.x+m4[i].y*a.y+m4[i].z*a.z+m4[i].w*a.w;
      a = wihL[(2*16+j4)*64+o];
      #pragma unroll
      for(int i=0;i<4;i++) in_[i] += m4[i].x*a.x+m4[i].y*a.y+m4[i].z*a.z+m4[i].w*a.w;
      a = whhL[(0*16+j4)*64+o];
      #pragma unroll
      for(int i=0;i<4;i++) hr[i]  += h4[i].x*a.x+h4[i].y*a.y+h4[i].z*a.z+h4[i].w*a.w;
      a = whhL[(1*16+j4)*64+o];
      #pragma unroll
      for(int i=0;i<4;i++) hz[i]  += h4[i].x*a.x+h4[i].y*a.y+h4[i].z*a.z+h4[i].w*a.w;
      a = whhL[(2*16+j4)*64+o];
      #pragma unroll
      for(int i=0;i<4;i++) hn[i]  += h4[i].x*a.x+h4[i].y*a.y+h4[i].z*a.z+h4[i].w*a.w;
    }
    #pragma unroll
    for(int i=0;i<4;i++){
      int n = n0 + i;
      float r  = sigmoidf(ir[i] + hr[i]);
      float z  = sigmoidf(iz[i] + hz[i]);
      float ngv= tanhf(in_[i] + r*hn[i]);
      float hnew = (1.f - z)*ngv + z*outs[g*4+i][o];
      if(n < N_NODES){
        outF[(size_t)n*64+o] = hnew;
        outB[(size_t)n*64+o] = f2b(hnew);
      }
    }
  }
}

// ---------------- stem head ----------------
__global__ __launch_bounds__(512) void k_stem(const float* __restrict__ outF, const int* __restrict__ sidx,
                                              const float4* __restrict__ s1P, const float* __restrict__ s1b,
                                              const float4* __restrict__ s2P, const float* __restrict__ s2b,
                                              void* __restrict__ dout, const int* __restrict__ flag){
  int grp = threadIdx.x >> 7, t = threadIdx.x & 127;
  int s = blockIdx.x*4 + grp;
  int isf = *flag;
  __shared__ __align__(16) float xs[4][64], hid[4][64];
  int a = sidx[s];
  if(t < 64) xs[grp][t] = outF[(size_t)a*64 + t];
  __syncthreads();
  if(t < 64){
    float acc = s1b[t];
    const float4* xp = (const float4*)xs[grp];
    #pragma unroll 8
    for(int j4=0;j4<16;j4++){
      float4 w = s1P[j4*64+t];
      float4 x = xp[j4];
      acc += w.x*x.x + w.y*x.y + w.z*x.z + w.w*x.w;
    }
    hid[grp][t] = lrelu(acc);
  }
  __syncthreads();
  if(t < 105){
    float acc = s2b[t];
    const float4* hp = (const float4*)hid[grp];
    #pragma unroll 8
    for(int j4=0;j4<16;j4++){
      float4 w = s2P[j4*112+t];
      float4 h = hp[j4];
      acc += w.x*h.x + w.y*h.y + w.z*h.z + w.w*h.w;
    }
    store_out(dout, isf, OUT_STEM + s*105 + t, acc);
  }
}

// ---------------- jbond head ----------------
__global__ __launch_bounds__(512) void k_jbond(const float* __restrict__ outF, const int* __restrict__ jidx,
                                               const float4* __restrict__ j1P, const float* __restrict__ j1b,
                                               const float* __restrict__ j2w, const float* __restrict__ j2b,
                                               void* __restrict__ dout, const int* __restrict__ flag){
  int grp = threadIdx.x >> 7, t = threadIdx.x & 127;
  int jb = blockIdx.x*4 + grp;
  int isf = *flag;
  __shared__ __align__(16) float xs[4][2][64], hid[4][2][64];
  int at = t >> 6, k = t & 63;
  int a = jidx[jb*2 + at];
  xs[grp][at][k] = outF[(size_t)a*64 + k];
  __syncthreads();
  {
    float acc = j1b[k];
    const float4* xp = (const float4*)xs[grp][at];
    #pragma unroll 8
    for(int j4=0;j4<16;j4++){
      float4 w = j1P[j4*64+k];
      float4 x = xp[j4];
      acc += w.x*x.x + w.y*x.y + w.z*x.z + w.w*x.w;
    }
    hid[grp][at][k] = lrelu(acc);
  }
  __syncthreads();
  if(t < 64){
    float p = (hid[grp][0][t] + hid[grp][1][t]) * j2w[t];
    #pragma unroll
    for(int s=32;s;s>>=1) p += __shfl_xor(p, s, 64);
    if(t==0) store_out(dout, isf, OUT_JB + jb, 0.5f*p + j2b[0]);
  }
}

// ---------------- Set2Set + final linear ----------------
__global__ __launch_bounds__(64) void k_s2s(const float* __restrict__ outF, const int* __restrict__ batch,
                                            const float* __restrict__ bih, const float* __restrict__ bhh,
                                            const float* __restrict__ loutw, const float* __restrict__ loutb,
                                            void* __restrict__ dout, const int* __restrict__ flag){
  int b = blockIdx.x, t = threadIdx.x;
  int isf = *flag;
  float i_ = bih[t]     + bhh[t];
  float g_ = bih[128+t] + bhh[128+t];
  float o_ = bih[192+t] + bhh[192+t];
  float c  = sigmoidf(i_)*tanhf(g_);
  float q  = sigmoidf(o_)*tanhf(c);

  int lo = lower_bound_i(batch, N_NODES, b);
  int hi = lower_bound_i(batch, N_NODES, b+1);

  float emax = -3.4e38f;
  for(int n=lo;n<hi;n++){
    float p = outF[n*64+t]*q;
    #pragma unroll
    for(int s=32;s;s>>=1) p += __shfl_xor(p, s, 64);
    emax = fmaxf(emax, p);
  }
  float Z = 0.f, racc = 0.f;
  for(int n=lo;n<hi;n++){
    float v = outF[n*64+t];
    float p = v*q;
    #pragma unroll
    for(int s=32;s;s>>=1) p += __shfl_xor(p, s, 64);
    float w = expf(p - emax);
    Z += w; racc += w*v;
  }
  float rp = (hi>lo) ? racc/Z : 0.f;

  #pragma unroll
  for(int j=0;j<2;j++){
    float p = q*loutw[j*128+t] + rp*loutw[j*128+64+t];
    #pragma unroll
    for(int s=32;s;s>>=1) p += __shfl_xor(p, s, 64);
    if(t==0) store_out(dout, isf, OUT_FINAL + b*2 + j, p + loutb[j]);
  }
}

extern "C" void kernel_launch(void* const* d_in, const int* in_sizes, int n_in,
                              void* d_out, int out_size, void* d_ws, size_t ws_size,
                              hipStream_t stream) {
  const int* edge_index  = (const int*)d_in[28];
  const int* stem_atmidx = (const int*)d_in[29];
  const int* jbond_atmidx= (const int*)d_in[30];
  const int* batch       = (const int*)d_in[31];

  char* ws = (char*)d_ws;
  size_t off = 0;
  auto alloc = [&](size_t bytes)->void*{ void* p = ws + off; off = (off + bytes + 255) & ~(size_t)255; return p; };

  int*   flag = (int*)  alloc(4);
  float* outF = (float*)alloc((size_t)PADN*64*4);
  u16*   outB = (u16*)  alloc((size_t)PADN*64*2);
  float* agg  = (float*)alloc((size_t)PADN*64*4);
  u16*   a1b  = (u16*)  alloc((size_t)N_EDGES*A1S*2);
  u16*   B2b  = (u16*)  alloc((size_t)KCH*2048*2);
  float* deg  = (float*)alloc((size_t)PADN*4);
  float4* rootP = (float4*)alloc(1024*16);
  float4* wihP  = (float4*)alloc(3072*16);
  float4* whhP  = (float4*)alloc(3072*16);
  float4* s1P   = (float4*)alloc(1024*16);
  float4* s2P   = (float4*)alloc(1792*16);
  float4* j1P   = (float4*)alloc(1024*16);

  static const int cvt_idx[N_CVT] = {0,1,2,3,4,5,6,7,8,9,10,11,12,13,14,15,16,17,18,19,20,21,24,25,26,27};
  CvtArgs A;
  float* cF[N_CVT];
  for(int i=0;i<N_CVT;i++){
    int src = cvt_idx[i];
    int n = in_sizes[src];
    cF[i] = (float*)alloc((size_t)n*4);
    A.src[i] = d_in[src];
    A.dst[i] = cF[i];
    A.n[i]   = n;
  }
  (void)ws_size; (void)n_in; (void)out_size;
  float* xF=cF[0];   float* eaF=cF[1];  float* l0w=cF[2];  float* l0b=cF[3];
  float* e1w=cF[4];  float* e1b=cF[5];  float* e2w=cF[6];  float* e2b=cF[7];
  float* rootw=cF[8];float* convb=cF[9];
  float* wih=cF[10]; float* whh=cF[11]; float* bih=cF[12]; float* bhh=cF[13];
  float* s1w=cF[14]; float* s1b=cF[15]; float* s2w=cF[16]; float* s2b=cF[17];
  float* j1w=cF[18]; float* j1b=cF[19]; float* j2w=cF[20]; float* j2b=cF[21];
  float* lbih=cF[22];float* lbhh=cF[23];float* loutw=cF[24];float* loutb=cF[25];

  hipMemsetAsync(flag, 0, 4, stream);
  hipMemsetAsync(deg,  0, (size_t)PADN*4, stream);
  hipMemsetAsync(outF + (size_t)N_NODES*64, 0, (size_t)(PADN-N_NODES)*64*4, stream);
  hipMemsetAsync(outB + (size_t)N_NODES*64, 0, (size_t)(PADN-N_NODES)*64*2, stream);
  hipMemsetAsync(agg,  0, (size_t)PADN*64*4, stream);

  k_sniff <<<128, 256, 0, stream>>>((const u16*)d_in[0], in_sizes[0], flag);
  k_cvt   <<<512, 256, 0, stream>>>(A, flag);

  k_lin0    <<<N_NODES, 64, 0, stream>>>(xF, l0w, l0b, outF, outB);
  k_a1      <<<N_EDGES, 128, 0, stream>>>(eaF, e1w, e1b, a1b);
  k_packW2b <<<(KCH*2048+255)/256, 256, 0, stream>>>(e2w, e2b, B2b);
  k_packRoot<<<4, 256, 0, stream>>>(rootw, rootP);
  k_packGates<<<12, 256, 0, stream>>>(wih, whh, wihP, whhP);
  k_packHeads<<<7, 256, 0, stream>>>(s1w, s2w, j1w, s1P, s2P, j1P);
  k_deg     <<<(N_EDGES+255)/256, 256, 0, stream>>>(edge_index + N_EDGES, deg);

  for(int it=0; it<6; it++){
    k_egemm<<<EGRID2*2, 256, 0, stream>>>(outB, a1b, B2b, edge_index, agg);
    k_node <<<NGRID, 512, 0, stream>>>(agg, deg, outF, outB, rootP, convb, wihP, whhP, bih, bhh);
  }

  k_stem <<<N_STEMS/4, 512, 0, stream>>>(outF, stem_atmidx, s1P, s1b, s2P, s2b, d_out, flag);
  k_jbond<<<N_JBONDS/4, 512, 0, stream>>>(outF, jbond_atmidx, j1P, j1b, j2w, j2b, d_out, flag);
  k_s2s  <<<NUM_GRAPHS, 64, 0, stream>>>(outF, batch, lbih, lbhh, loutw, loutb, d_out, flag);
}

// Round 19
// 700.757 us; speedup vs baseline: 1.0712x; 1.0712x over previous
//
#include <hip/hip_runtime.h>

typedef unsigned short u16;
typedef unsigned int   u32;

#define N_NODES    15000
#define PADN       15008
#define N_EDGES    30000
#define NUM_GRAPHS 600
#define N_STEMS    6000
#define N_JBONDS   3000

#define OUT_FINAL  0
#define OUT_STEM   1200
#define OUT_JB     631200

#define A1S 68                // a1b (global) row stride u16
#define N_CVT 26

// ---- edge-GEMM geometry ----
#define EBLK 64               // edges per block
#define EGRID2 469            // ceil(30000/64)
#define KCH 130               // K chunks of 32 (K = 65*64 = 4160, kidx = k*64 + j)
#define KHALF 65              // chunks per K-half
#define A1LS 66               // a1l row stride u16
#define O2S 66                // outs2 row stride dw (== 2 mod 32 -> 2-way (free) A-gen reads)

// ---- k_node geometry ----
#define NGRID 235
#define NGROUPS (PADN/16)     // 938 groups of 16 nodes

typedef short frag8 __attribute__((ext_vector_type(8)));   // 8 bf16
typedef float facc4 __attribute__((ext_vector_type(4)));   // 4 f32 acc

__device__ __forceinline__ float u2f(u16 v){ union{u32 i; float f;} c; c.i=((u32)v)<<16; return c.f; }
__device__ __forceinline__ float blo(u32 x){ union{u32 i; float f;} c; c.i=x<<16; return c.f; }
__device__ __forceinline__ float bhi(u32 x){ union{u32 i; float f;} c; c.i=x&0xffff0000u; return c.f; }
__device__ __forceinline__ u16  f2b(float f){ union{float f; u32 u;} c; c.f=f; u32 u=c.u;
                                              return (u16)((u + 0x7fffu + ((u>>16)&1u))>>16); }
__device__ __forceinline__ float lrelu(float x){ return x>0.f ? x : 0.01f*x; }
__device__ __forceinline__ float sigmoidf(float x){ return 1.f/(1.f+expf(-x)); }

__device__ __forceinline__ int lower_bound_i(const int* __restrict__ a, int n, int v){
  int lo=0, hi=n;
  while(lo<hi){ int m=(lo+hi)>>1; if(a[m]<v) lo=m+1; else hi=m; }
  return lo;
}

__device__ __forceinline__ void store_out(void* dout, int isf, int idx, float v){
  if(isf) ((float*)dout)[idx] = v;
  else    ((u16*)dout)[idx]   = f2b(v);
}

// ---------------- dtype sniff ----------------
__global__ __launch_bounds__(256) void k_sniff(const u16* __restrict__ x, int n, int* __restrict__ flag){
  int i = blockIdx.x*256 + threadIdx.x;
  int local = 0;
  for(; i < n; i += gridDim.x*256){
    u16 v = x[i];
    if(((v>>7)&0xFFu) == 0xFFu) local = 1;
  }
  if(local) atomicOr(flag, 1);
}

// ---------------- convert float inputs to f32 ----------------
struct CvtArgs { const void* src[N_CVT]; float* dst[N_CVT]; int n[N_CVT]; };

__global__ __launch_bounds__(256) void k_cvt(CvtArgs A, const int* __restrict__ flag){
  int isf = *flag;
  int tid = blockIdx.x*256 + threadIdx.x;
  int stride = gridDim.x*256;
  for(int b=0; b<N_CVT; b++){
    int n = A.n[b];
    const float* sf = (const float*)A.src[b];
    const u16*   sb = (const u16*)A.src[b];
    float* d = A.dst[b];
    for(int i=tid; i<n; i+=stride) d[i] = isf ? sf[i] : u2f(sb[i]);
  }
}

// ---------------- lin0 (writes f32 out + bf16 mirror) ----------------
__global__ __launch_bounds__(64) void k_lin0(const float* __restrict__ x, const float* __restrict__ w,
                                             const float* __restrict__ b,
                                             float* __restrict__ outF, u16* __restrict__ outB){
  int n = blockIdx.x, o = threadIdx.x;
  __shared__ float xs[14];
  if(o<14) xs[o] = x[n*14+o];
  __syncthreads();
  float acc = b[o];
  #pragma unroll
  for(int i=0;i<14;i++) acc += xs[i]*w[o*14+i];
  float v = lrelu(acc);
  outF[n*64+o] = v;
  outB[n*64+o] = f2b(v);
}

// ---------------- a1b[e][A1S] bf16 ----------------
__global__ __launch_bounds__(128) void k_a1(const float* __restrict__ ea,
                                            const float* __restrict__ en1w, const float* __restrict__ en1b,
                                            u16* __restrict__ a1b){
  int e = blockIdx.x, k = threadIdx.x;
  if(k >= A1S) return;
  float v = 0.f;
  if(k < 64){
    float acc = en1b[k];
    #pragma unroll
    for(int c=0;c<4;c++) acc += ea[e*4+c] * en1w[k*4+c];
    v = lrelu(acc);
  } else if(k == 64) v = 1.0f;
  a1b[e*A1S + k] = f2b(v);
}

// ---------------- B2b: bf16 B-operand, FRAGMENT-LINEAR order ----------------
__global__ __launch_bounds__(256) void k_packW2b(const float* __restrict__ en2w, const float* __restrict__ en2b,
                                                 u16* __restrict__ B2b){
  int idx = blockIdx.x*256 + threadIdx.x;
  if(idx >= KCH*2048) return;
  int jj  = idx & 7;
  int l   = (idx >> 3) & 63;
  int nt  = (idx >> 9) & 3;
  int c   = idx >> 11;
  int q = l >> 4, m16 = l & 15;
  int kidx = c*32 + q*8 + jj;
  int k = kidx >> 6, j = kidx & 63;
  int o = nt*16 + m16;
  float v = (k < 64) ? en2w[((size_t)(j*64 + o))*64 + k] : en2b[j*64 + o];
  B2b[idx] = f2b(v);
}

// ---------------- packed coalesced weights for k_node ----------------
__global__ __launch_bounds__(256) void k_packRoot(const float* __restrict__ root, float4* __restrict__ rootP){
  int idx = blockIdx.x*256 + threadIdx.x;
  if(idx >= 1024) return;
  int o = idx & 63, j4 = idx >> 6;
  float4 v;
  v.x = root[(4*j4+0)*64 + o];
  v.y = root[(4*j4+1)*64 + o];
  v.z = root[(4*j4+2)*64 + o];
  v.w = root[(4*j4+3)*64 + o];
  rootP[idx] = v;
}

__global__ __launch_bounds__(256) void k_packGates(const float* __restrict__ wih, const float* __restrict__ whh,
                                                   float4* __restrict__ wihP, float4* __restrict__ whhP){
  int idx = blockIdx.x*256 + threadIdx.x;
  if(idx >= 3072) return;
  int o = idx & 63, j4 = (idx >> 6) & 15, g = idx >> 10;
  int row = (g*64 + o)*64 + 4*j4;
  float4 a, b;
  a.x = wih[row+0]; a.y = wih[row+1]; a.z = wih[row+2]; a.w = wih[row+3];
  b.x = whh[row+0]; b.y = whh[row+1]; b.z = whh[row+2]; b.w = whh[row+3];
  wihP[idx] = a; whhP[idx] = b;
}

// ---------------- packed coalesced head weights ----------------
__global__ __launch_bounds__(256) void k_packHeads(const float* __restrict__ s1w, const float* __restrict__ s2w,
                                                   const float* __restrict__ j1w,
                                                   float4* __restrict__ s1P, float4* __restrict__ s2P,
                                                   float4* __restrict__ j1P){
  int idx = blockIdx.x*256 + threadIdx.x;
  if(idx < 1024){
    int o = idx & 63, j4 = idx >> 6;
    const float* r = s1w + o*64 + 4*j4;
    s1P[idx] = (float4){r[0], r[1], r[2], r[3]};
    const float* r2 = j1w + o*64 + 4*j4;
    j1P[idx] = (float4){r2[0], r2[1], r2[2], r2[3]};
  }
  if(idx < 1792){
    int j4 = idx / 112, t = idx % 112;
    float4 v = {0.f,0.f,0.f,0.f};
    if(t < 105){
      const float* r = s2w + t*64 + 4*j4;
      v = (float4){r[0], r[1], r[2], r[3]};
    }
    s2P[idx] = v;
  }
}

// ---------------- deg ----------------
__global__ __launch_bounds__(256) void k_deg(const int* __restrict__ dst, float* __restrict__ deg){
  int e = blockIdx.x*256 + threadIdx.x;
  if(e < N_EDGES) atomicAdd(&deg[dst[e]], 1.0f);
}

// ---------------- edge-GEMM v4 (unchanged) ----------------
__global__ __launch_bounds__(256, 2) void k_egemm(const u16* __restrict__ outB,
                                               const u16* __restrict__ a1b,
                                               const u16* __restrict__ B2b,
                                               const int* __restrict__ ei,
                                               float* __restrict__ agg){
  int tid = threadIdx.x;
  int l = tid & 63, w = tid >> 6;
  int m16 = l & 15, q = l >> 4;
  int half = blockIdx.x & 1;
  int eb = (blockIdx.x >> 1) * EBLK;

  __shared__ __align__(16) u16 a1l[EBLK*A1LS];
  __shared__ __align__(16) u32 outs2[32*O2S];
  __shared__ __align__(16) u16 Bl[4*2048];
  __shared__ int dstl[EBLK];

  for(int i = tid; i < EBLK; i += 256){
    int e = eb + i;
    dstl[i] = (e < N_EDGES) ? ei[N_EDGES + e] : -1;
  }
  for(int idx = tid; idx < EBLK*33; idx += 256){
    int r = idx / 33, c = idx - r*33;
    int e = eb + r;
    u32 v = (e < N_EDGES) ? ((const u32*)(a1b + (size_t)e*A1S))[c] : 0u;
    ((u32*)a1l)[r*33 + c] = v;
  }
  for(int idx = tid; idx < EBLK*8; idx += 256){
    int r = idx >> 3, part = idx & 7;
    int e = eb + r;
    int node = (e < N_EDGES) ? ei[e] : 0;
    uint4 v = *(const uint4*)(outB + (size_t)node*64 + part*8);
    outs2[(part*4+0)*O2S + r] = v.x;
    outs2[(part*4+1)*O2S + r] = v.y;
    outs2[(part*4+2)*O2S + r] = v.z;
    outs2[(part*4+3)*O2S + r] = v.w;
  }
  __syncthreads();

  facc4 acc[4];
  #pragma unroll
  for(int nt=0;nt<4;nt++) acc[nt] = (facc4){0.f,0.f,0.f,0.f};

  int el0 = w*16 + m16;
  int cbase = half * KHALF;
  for(int rr = 0; rr < 17; rr++){
    int c0 = rr*4;
    int nch = KHALF - c0; if(nch > 4) nch = 4;
    {
      const uint4* src = (const uint4*)(B2b + (size_t)(cbase + c0)*2048);
      for(int i = tid; i < nch*256; i += 256) ((uint4*)Bl)[i] = src[i];
    }
    __syncthreads();
    for(int cc = 0; cc < nch; cc++){
      int c = cbase + c0 + cc;
      int k = c >> 1;
      int jdw0 = ((c & 1) << 4) + (q << 2);
      float av = u2f(a1l[el0*A1LS + k]);
      union { u32 d[4]; frag8 f; } au;
      #pragma unroll
      for(int i=0;i<4;i++){
        u32 d0 = outs2[(jdw0+i)*O2S + el0];
        float plo = blo(d0)*av, phi = bhi(d0)*av;
        au.d[i] = __builtin_amdgcn_perm(__float_as_uint(phi)+0x8000u,
                                        __float_as_uint(plo)+0x8000u, 0x07060302u);
      }
      #pragma unroll
      for(int nt = 0; nt < 4; nt++){
        frag8 bf = *(const frag8*)(Bl + ((size_t)((cc*4 + nt)*64 + l))*8);
        acc[nt] = __builtin_amdgcn_mfma_f32_16x16x32_bf16(au.f, bf, acc[nt], 0,0,0);
      }
    }
    __syncthreads();
  }

  #pragma unroll
  for(int nt = 0; nt < 4; nt++){
    #pragma unroll
    for(int r = 0; r < 4; r++){
      int el = w*16 + q*4 + r;
      int dst = dstl[el];
      if(dst >= 0) atomicAdd(&agg[(size_t)dst*64 + nt*16 + m16], acc[nt][r]);
    }
  }
}

// ---------------- node update v9 (reverted from v10): persistent, 16-node groups, 2 nodes/thread ----------------
// nn=2 is the empirical optimum: nn=1 (r14) and nn=4 (r18) both slower.
__global__ __launch_bounds__(512, 1) void k_node(float* __restrict__ agg, const float* __restrict__ deg,
                                              float* __restrict__ outF, u16* __restrict__ outB,
                                              const float4* __restrict__ rootP, const float* __restrict__ convb,
                                              const float4* __restrict__ wihP, const float4* __restrict__ whhP,
                                              const float* __restrict__ bih, const float* __restrict__ bhh){
  int o = threadIdx.x & 63, g = threadIdx.x >> 6;
  __shared__ __align__(16) float outs[16][64], ms[16][64];
  __shared__ __align__(16) float4 rootL[1024];
  __shared__ __align__(16) float4 wihL[3072];
  __shared__ __align__(16) float4 whhL[3072];

  for(int i = threadIdx.x; i < 1024; i += 512) rootL[i] = rootP[i];
  for(int i = threadIdx.x; i < 3072; i += 512){ wihL[i] = wihP[i]; whhL[i] = whhP[i]; }
  float cb = convb[o];
  float b0 = bih[o], b1 = bih[64+o], b2 = bih[128+o];
  float c0 = bhh[o], c1 = bhh[64+o], c2 = bhh[128+o];

  for(int ng = blockIdx.x; ng < NGROUPS; ng += gridDim.x){
    int nb = ng * 16;
    __syncthreads();
    for(int i = threadIdx.x; i < 256; i += 512)
      ((float4*)outs)[i] = ((const float4*)(outF + (size_t)nb*64))[i];
    __syncthreads();

    int n0 = nb + g*2, n1 = n0 + 1;
    const float4* op0 = (const float4*)outs[g*2];
    const float4* op1 = (const float4*)outs[g*2+1];

    float acc0 = agg[(size_t)n0*64+o] / fmaxf(deg[n0], 1.0f) + cb;
    float acc1 = agg[(size_t)n1*64+o] / fmaxf(deg[n1], 1.0f) + cb;
    agg[(size_t)n0*64+o] = 0.f;
    agg[(size_t)n1*64+o] = 0.f;
    #pragma unroll 4
    for(int j4=0;j4<16;j4++){
      float4 w = rootL[j4*64+o];
      float4 m0 = op0[j4], m1 = op1[j4];
      acc0 += w.x*m0.x + w.y*m0.y + w.z*m0.z + w.w*m0.w;
      acc1 += w.x*m1.x + w.y*m1.y + w.z*m1.z + w.w*m1.w;
    }
    ms[g*2][o]   = lrelu(acc0);
    ms[g*2+1][o] = lrelu(acc1);
    __syncthreads();

    float ir0=b0, iz0=b1, in0=b2, hr0=c0, hz0=c1, hn0=c2;
    float ir1=b0, iz1=b1, in1=b2, hr1=c0, hz1=c1, hn1=c2;
    const float4* mp0 = (const float4*)ms[g*2];
    const float4* mp1 = (const float4*)ms[g*2+1];
    #pragma unroll 4
    for(int j4=0;j4<16;j4++){
      float4 m40 = mp0[j4], m41 = mp1[j4], h40 = op0[j4], h41 = op1[j4];
      float4 a;
      a = wihL[(0*16+j4)*64+o];
      ir0 += m40.x*a.x+m40.y*a.y+m40.z*a.z+m40.w*a.w;
      ir1 += m41.x*a.x+m41.y*a.y+m41.z*a.z+m41.w*a.w;
      a = wihL[(1*16+j4)*64+o];
      iz0 += m40.x*a.x+m40.y*a.y+m40.z*a.z+m40.w*a.w;
      iz1 += m41.x*a.x+m41.y*a.y+m41.z*a.z+m41.w*a.w;
      a = wihL[(2*16+j4)*64+o];
      in0 += m40.x*a.x+m40.y*a.y+m40.z*a.z+m40.w*a.w;
      in1 += m41.x*a.x+m41.y*a.y+m41.z*a.z+m41.w*a.w;
      a = whhL[(0*16+j4)*64+o];
      hr0 += h40.x*a.x+h40.y*a.y+h40.z*a.z+h40.w*a.w;
      hr1 += h41.x*a.x+h41.y*a.y+h41.z*a.z+h41.w*a.w;
      a = whhL[(1*16+j4)*64+o];
      hz0 += h40.x*a.x+h40.y*a.y+h40.z*a.z+h40.w*a.w;
      hz1 += h41.x*a.x+h41.y*a.y+h41.z*a.z+h41.w*a.w;
      a = whhL[(2*16+j4)*64+o];
      hn0 += h40.x*a.x+h40.y*a.y+h40.z*a.z+h40.w*a.w;
      hn1 += h41.x*a.x+h41.y*a.y+h41.z*a.z+h41.w*a.w;
    }
    {
      float r  = sigmoidf(ir0+hr0);
      float z  = sigmoidf(iz0+hz0);
      float ngv= tanhf(in0 + r*hn0);
      float hnew = (1.f - z)*ngv + z*outs[g*2][o];
      if(n0 < N_NODES){
        outF[(size_t)n0*64+o] = hnew;
        outB[(size_t)n0*64+o] = f2b(hnew);
      }
    }
    {
      float r  = sigmoidf(ir1+hr1);
      float z  = sigmoidf(iz1+hz1);
      float ngv= tanhf(in1 + r*hn1);
      float hnew = (1.f - z)*ngv + z*outs[g*2+1][o];
      if(n1 < N_NODES){
        outF[(size_t)n1*64+o] = hnew;
        outB[(size_t)n1*64+o] = f2b(hnew);
      }
    }
  }
}

// ---------------- stem head ----------------
__global__ __launch_bounds__(512) void k_stem(const float* __restrict__ outF, const int* __restrict__ sidx,
                                              const float4* __restrict__ s1P, const float* __restrict__ s1b,
                                              const float4* __restrict__ s2P, const float* __restrict__ s2b,
                                              void* __restrict__ dout, const int* __restrict__ flag){
  int grp = threadIdx.x >> 7, t = threadIdx.x & 127;
  int s = blockIdx.x*4 + grp;
  int isf = *flag;
  __shared__ __align__(16) float xs[4][64], hid[4][64];
  int a = sidx[s];
  if(t < 64) xs[grp][t] = outF[(size_t)a*64 + t];
  __syncthreads();
  if(t < 64){
    float acc = s1b[t];
    const float4* xp = (const float4*)xs[grp];
    #pragma unroll 8
    for(int j4=0;j4<16;j4++){
      float4 w = s1P[j4*64+t];
      float4 x = xp[j4];
      acc += w.x*x.x + w.y*x.y + w.z*x.z + w.w*x.w;
    }
    hid[grp][t] = lrelu(acc);
  }
  __syncthreads();
  if(t < 105){
    float acc = s2b[t];
    const float4* hp = (const float4*)hid[grp];
    #pragma unroll 8
    for(int j4=0;j4<16;j4++){
      float4 w = s2P[j4*112+t];
      float4 h = hp[j4];
      acc += w.x*h.x + w.y*h.y + w.z*h.z + w.w*h.w;
    }
    store_out(dout, isf, OUT_STEM + s*105 + t, acc);
  }
}

// ---------------- jbond head ----------------
__global__ __launch_bounds__(512) void k_jbond(const float* __restrict__ outF, const int* __restrict__ jidx,
                                               const float4* __restrict__ j1P, const float* __restrict__ j1b,
                                               const float* __restrict__ j2w, const float* __restrict__ j2b,
                                               void* __restrict__ dout, const int* __restrict__ flag){
  int grp = threadIdx.x >> 7, t = threadIdx.x & 127;
  int jb = blockIdx.x*4 + grp;
  int isf = *flag;
  __shared__ __align__(16) float xs[4][2][64], hid[4][2][64];
  int at = t >> 6, k = t & 63;
  int a = jidx[jb*2 + at];
  xs[grp][at][k] = outF[(size_t)a*64 + k];
  __syncthreads();
  {
    float acc = j1b[k];
    const float4* xp = (const float4*)xs[grp][at];
    #pragma unroll 8
    for(int j4=0;j4<16;j4++){
      float4 w = j1P[j4*64+k];
      float4 x = xp[j4];
      acc += w.x*x.x + w.y*x.y + w.z*x.z + w.w*x.w;
    }
    hid[grp][at][k] = lrelu(acc);
  }
  __syncthreads();
  if(t < 64){
    float p = (hid[grp][0][t] + hid[grp][1][t]) * j2w[t];
    #pragma unroll
    for(int s=32;s;s>>=1) p += __shfl_xor(p, s, 64);
    if(t==0) store_out(dout, isf, OUT_JB + jb, 0.5f*p + j2b[0]);
  }
}

// ---------------- Set2Set + final linear ----------------
__global__ __launch_bounds__(64) void k_s2s(const float* __restrict__ outF, const int* __restrict__ batch,
                                            const float* __restrict__ bih, const float* __restrict__ bhh,
                                            const float* __restrict__ loutw, const float* __restrict__ loutb,
                                            void* __restrict__ dout, const int* __restrict__ flag){
  int b = blockIdx.x, t = threadIdx.x;
  int isf = *flag;
  float i_ = bih[t]     + bhh[t];
  float g_ = bih[128+t] + bhh[128+t];
  float o_ = bih[192+t] + bhh[192+t];
  float c  = sigmoidf(i_)*tanhf(g_);
  float q  = sigmoidf(o_)*tanhf(c);

  int lo = lower_bound_i(batch, N_NODES, b);
  int hi = lower_bound_i(batch, N_NODES, b+1);

  float emax = -3.4e38f;
  for(int n=lo;n<hi;n++){
    float p = outF[n*64+t]*q;
    #pragma unroll
    for(int s=32;s;s>>=1) p += __shfl_xor(p, s, 64);
    emax = fmaxf(emax, p);
  }
  float Z = 0.f, racc = 0.f;
  for(int n=lo;n<hi;n++){
    float v = outF[n*64+t];
    float p = v*q;
    #pragma unroll
    for(int s=32;s;s>>=1) p += __shfl_xor(p, s, 64);
    float w = expf(p - emax);
    Z += w; racc += w*v;
  }
  float rp = (hi>lo) ? racc/Z : 0.f;

  #pragma unroll
  for(int j=0;j<2;j++){
    float p = q*loutw[j*128+t] + rp*loutw[j*128+64+t];
    #pragma unroll
    for(int s=32;s;s>>=1) p += __shfl_xor(p, s, 64);
    if(t==0) store_out(dout, isf, OUT_FINAL + b*2 + j, p + loutb[j]);
  }
}

extern "C" void kernel_launch(void* const* d_in, const int* in_sizes, int n_in,
                              void* d_out, int out_size, void* d_ws, size_t ws_size,
                              hipStream_t stream) {
  const int* edge_index  = (const int*)d_in[28];
  const int* stem_atmidx = (const int*)d_in[29];
  const int* jbond_atmidx= (const int*)d_in[30];
  const int* batch       = (const int*)d_in[31];

  char* ws = (char*)d_ws;
  size_t off = 0;
  auto alloc = [&](size_t bytes)->void*{ void* p = ws + off; off = (off + bytes + 255) & ~(size_t)255; return p; };

  int*   flag = (int*)  alloc(4);
  float* outF = (float*)alloc((size_t)PADN*64*4);
  u16*   outB = (u16*)  alloc((size_t)PADN*64*2);
  float* agg  = (float*)alloc((size_t)PADN*64*4);
  u16*   a1b  = (u16*)  alloc((size_t)N_EDGES*A1S*2);
  u16*   B2b  = (u16*)  alloc((size_t)KCH*2048*2);
  float* deg  = (float*)alloc((size_t)PADN*4);
  float4* rootP = (float4*)alloc(1024*16);
  float4* wihP  = (float4*)alloc(3072*16);
  float4* whhP  = (float4*)alloc(3072*16);
  float4* s1P   = (float4*)alloc(1024*16);
  float4* s2P   = (float4*)alloc(1792*16);
  float4* j1P   = (float4*)alloc(1024*16);

  static const int cvt_idx[N_CVT] = {0,1,2,3,4,5,6,7,8,9,10,11,12,13,14,15,16,17,18,19,20,21,24,25,26,27};
  CvtArgs A;
  float* cF[N_CVT];
  for(int i=0;i<N_CVT;i++){
    int src = cvt_idx[i];
    int n = in_sizes[src];
    cF[i] = (float*)alloc((size_t)n*4);
    A.src[i] = d_in[src];
    A.dst[i] = cF[i];
    A.n[i]   = n;
  }
  (void)ws_size; (void)n_in; (void)out_size;
  float* xF=cF[0];   float* eaF=cF[1];  float* l0w=cF[2];  float* l0b=cF[3];
  float* e1w=cF[4];  float* e1b=cF[5];  float* e2w=cF[6];  float* e2b=cF[7];
  float* rootw=cF[8];float* convb=cF[9];
  float* wih=cF[10]; float* whh=cF[11]; float* bih=cF[12]; float* bhh=cF[13];
  float* s1w=cF[14]; float* s1b=cF[15]; float* s2w=cF[16]; float* s2b=cF[17];
  float* j1w=cF[18]; float* j1b=cF[19]; float* j2w=cF[20]; float* j2b=cF[21];
  float* lbih=cF[22];float* lbhh=cF[23];float* loutw=cF[24];float* loutb=cF[25];

  hipMemsetAsync(flag, 0, 4, stream);
  hipMemsetAsync(deg,  0, (size_t)PADN*4, stream);
  hipMemsetAsync(outF + (size_t)N_NODES*64, 0, (size_t)(PADN-N_NODES)*64*4, stream);
  hipMemsetAsync(outB + (size_t)N_NODES*64, 0, (size_t)(PADN-N_NODES)*64*2, stream);
  hipMemsetAsync(agg,  0, (size_t)PADN*64*4, stream);

  k_sniff <<<128, 256, 0, stream>>>((const u16*)d_in[0], in_sizes[0], flag);
  k_cvt   <<<512, 256, 0, stream>>>(A, flag);

  k_lin0    <<<N_NODES, 64, 0, stream>>>(xF, l0w, l0b, outF, outB);
  k_a1      <<<N_EDGES, 128, 0, stream>>>(eaF, e1w, e1b, a1b);
  k_packW2b <<<(KCH*2048+255)/256, 256, 0, stream>>>(e2w, e2b, B2b);
  k_packRoot<<<4, 256, 0, stream>>>(rootw, rootP);
  k_packGates<<<12, 256, 0, stream>>>(wih, whh, wihP, whhP);
  k_packHeads<<<7, 256, 0, stream>>>(s1w, s2w, j1w, s1P, s2P, j1P);
  k_deg     <<<(N_EDGES+255)/256, 256, 0, stream>>>(edge_index + N_EDGES, deg);

  for(int it=0; it<6; it++){
    k_egemm<<<EGRID2*2, 256, 0, stream>>>(outB, a1b, B2b, edge_index, agg);
    k_node <<<NGRID, 512, 0, stream>>>(agg, deg, outF, outB, rootP, convb, wihP, whhP, bih, bhh);
  }

  k_stem <<<N_STEMS/4, 512, 0, stream>>>(outF, stem_atmidx, s1P, s1b, s2P, s2b, d_out, flag);
  k_jbond<<<N_JBONDS/4, 512, 0, stream>>>(outF, jbond_atmidx, j1P, j1b, j2w, j2b, d_out, flag);
  k_s2s  <<<NUM_GRAPHS, 64, 0, stream>>>(outF, batch, lbih, lbhh, loutw, loutb, d_out, flag);
}